// Round 1
// baseline (513.662 us; speedup 1.0000x reference)
//
#include <hip/hip_runtime.h>
#include <cstddef>

#define NB   16
#define CIN  512
#define NTOK 1600   // 40*40
#define HCH  64

// ---------------------------------------------------------------------------
// Kernel 1: projections. dst[b][n][h] = sum_c src[b][c][n] * w[c][h]
// blockIdx.x -> (b, 64-row n-tile), blockIdx.y -> which of {Q,K,V}
// ---------------------------------------------------------------------------
extern "C" __global__ void __launch_bounds__(256) proj_kernel(
    const float* __restrict__ rgb, const float* __restrict__ hsi,
    const float* __restrict__ wq, const float* __restrict__ wk,
    const float* __restrict__ wv,
    float* __restrict__ Q, float* __restrict__ K, float* __restrict__ V)
{
    const int which = blockIdx.y;
    const float* __restrict__ src = (which == 2) ? hsi : rgb;
    const float* __restrict__ w   = (which == 0) ? wq : (which == 1) ? wk : wv;
    float* __restrict__ dst       = (which == 0) ? Q  : (which == 1) ? K  : V;

    const int b   = blockIdx.x / 25;
    const int n0  = (blockIdx.x % 25) * 64;
    const int tid = threadIdx.x;
    const int tx  = tid & 15, ty = tid >> 4;

    __shared__ __align__(16) float As[16 * 64];   // [cc][nn]  (c-major: contraction = row)
    __shared__ __align__(16) float Ws[16 * 64];   // [cc][h]

    float acc[4][4] = {};

    const int cc_l = tid >> 4;   // 0..15  row this thread loads
    const int e4_l = tid & 15;   // 0..15  float4 within row

    for (int c0 = 0; c0 < CIN; c0 += 16) {
        __syncthreads();
        {
            const float* gs = src + ((size_t)b * CIN + (c0 + cc_l)) * NTOK + n0;
            ((float4*)As)[tid] = ((const float4*)gs)[e4_l];
            const float* gw = w + (size_t)(c0 + cc_l) * HCH;
            ((float4*)Ws)[tid] = ((const float4*)gw)[e4_l];
        }
        __syncthreads();
        #pragma unroll
        for (int cc = 0; cc < 16; ++cc) {
            const float4 a4 = ((const float4*)As)[cc * 16 + ty];  // broadcast within row-group
            const float4 b4 = ((const float4*)Ws)[cc * 16 + tx];  // 2-way, free
            const float aa[4] = {a4.x, a4.y, a4.z, a4.w};
            const float bb[4] = {b4.x, b4.y, b4.z, b4.w};
            #pragma unroll
            for (int i = 0; i < 4; ++i)
                #pragma unroll
                for (int j = 0; j < 4; ++j)
                    acc[i][j] += aa[i] * bb[j];
        }
    }

    #pragma unroll
    for (int i = 0; i < 4; ++i) {
        float4 o = make_float4(acc[i][0], acc[i][1], acc[i][2], acc[i][3]);
        *((float4*)(dst + ((size_t)b * NTOK + n0 + ty * 4 + i) * HCH + tx * 4)) = o;
    }
}

// ---------------------------------------------------------------------------
// Kernel 2: flash attention.  64 query rows per block, 25 key tiles of 64.
// R[b][n][h] = softmax_m(q_n . k_m / 8) @ V
// LDS: QsT[h][m], KsT[h][n] (transposed for conflict-free outer products),
//      Vs[m][h] natural, Ps[m][cc] with XOR float4-column swizzle. 64 KB total.
// ---------------------------------------------------------------------------
extern "C" __global__ void __launch_bounds__(256) attn_kernel(
    const float* __restrict__ Q, const float* __restrict__ K,
    const float* __restrict__ V, float* __restrict__ R)
{
    const int b   = blockIdx.x / 25;
    const int n0  = (blockIdx.x % 25) * 64;
    const int tid = threadIdx.x;
    const int tx  = tid & 15, ty = tid >> 4;

    __shared__ __align__(16) float QsT[64 * 64];
    __shared__ __align__(16) float KsT[64 * 64];
    __shared__ __align__(16) float Vs[64 * 64];
    __shared__ __align__(16) float Ps[64 * 64];

    // Load Q block transposed: QsT[h][m]
    #pragma unroll
    for (int k = 0; k < 4; ++k) {
        int e4 = tid + k * 256;       // 0..1023 float4s
        int r  = e4 >> 4;             // query row 0..63
        int h4 = e4 & 15;
        float4 q4 = ((const float4*)(Q + ((size_t)b * NTOK + n0 + r) * HCH))[h4];
        QsT[(h4 * 4 + 0) * 64 + r] = q4.x;
        QsT[(h4 * 4 + 1) * 64 + r] = q4.y;
        QsT[(h4 * 4 + 2) * 64 + r] = q4.z;
        QsT[(h4 * 4 + 3) * 64 + r] = q4.w;
    }

    float m_run[4], l_run[4], o_acc[4][4];
    #pragma unroll
    for (int i = 0; i < 4; ++i) {
        m_run[i] = -1e30f; l_run[i] = 0.f;
        #pragma unroll
        for (int j = 0; j < 4; ++j) o_acc[i][j] = 0.f;
    }

    for (int kt = 0; kt < 25; ++kt) {
        __syncthreads();   // previous tile's Ps/Vs/KsT fully consumed
        #pragma unroll
        for (int k = 0; k < 4; ++k) {
            int e4 = tid + k * 256;
            int r  = e4 >> 4;          // key index within tile
            int h4 = e4 & 15;
            const size_t gbase = ((size_t)b * NTOK + kt * 64 + r) * HCH;
            float4 k4 = ((const float4*)(K + gbase))[h4];
            KsT[(h4 * 4 + 0) * 64 + r] = k4.x;
            KsT[(h4 * 4 + 1) * 64 + r] = k4.y;
            KsT[(h4 * 4 + 2) * 64 + r] = k4.z;
            KsT[(h4 * 4 + 3) * 64 + r] = k4.w;
            ((float4*)Vs)[r * 16 + h4] = ((const float4*)(V + gbase))[h4];
        }
        __syncthreads();

        // S = Q K^T (outer products over h)
        float s[4][4] = {};
        #pragma unroll 8
        for (int h = 0; h < 64; ++h) {
            const float4 a4 = ((const float4*)QsT)[h * 16 + ty];  // broadcast
            const float4 b4 = ((const float4*)KsT)[h * 16 + tx];  // 2-way, free
            const float aa[4] = {a4.x, a4.y, a4.z, a4.w};
            const float bb[4] = {b4.x, b4.y, b4.z, b4.w};
            #pragma unroll
            for (int i = 0; i < 4; ++i)
                #pragma unroll
                for (int j = 0; j < 4; ++j)
                    s[i][j] += aa[i] * bb[j];
        }

        // Online softmax per row (16 threads share a row-group via shfl width 16)
        #pragma unroll
        for (int i = 0; i < 4; ++i) {
            float tmax = -1e30f;
            #pragma unroll
            for (int j = 0; j < 4; ++j) {
                s[i][j] *= 0.125f;                 // HC^-0.5
                tmax = fmaxf(tmax, s[i][j]);
            }
            #pragma unroll
            for (int msk = 1; msk < 16; msk <<= 1)
                tmax = fmaxf(tmax, __shfl_xor(tmax, msk, 16));
            const float m_new = fmaxf(m_run[i], tmax);
            const float alpha = __expf(m_run[i] - m_new);
            float rsum = 0.f;
            #pragma unroll
            for (int j = 0; j < 4; ++j) {
                s[i][j] = __expf(s[i][j] - m_new);
                rsum += s[i][j];
            }
            #pragma unroll
            for (int msk = 1; msk < 16; msk <<= 1)
                rsum += __shfl_xor(rsum, msk, 16);
            l_run[i] = l_run[i] * alpha + rsum;
            m_run[i] = m_new;
            #pragma unroll
            for (int j = 0; j < 4; ++j) o_acc[i][j] *= alpha;
            // Write P row, XOR-swizzled float4 column -> 2-way banks on r/w
            const int m = ty * 4 + i;
            ((float4*)Ps)[m * 16 + (tx ^ (m & 15))] =
                make_float4(s[i][0], s[i][1], s[i][2], s[i][3]);
        }
        __syncthreads();

        // O += P @ V
        #pragma unroll 4
        for (int c4 = 0; c4 < 16; ++c4) {
            float vv[4][4];
            #pragma unroll
            for (int u = 0; u < 4; ++u) {
                const float4 v4 = ((const float4*)Vs)[(c4 * 4 + u) * 16 + tx];
                vv[u][0] = v4.x; vv[u][1] = v4.y; vv[u][2] = v4.z; vv[u][3] = v4.w;
            }
            #pragma unroll
            for (int i = 0; i < 4; ++i) {
                const int m = ty * 4 + i;
                const float4 p4 = ((const float4*)Ps)[m * 16 + (c4 ^ (m & 15))];
                const float pp[4] = {p4.x, p4.y, p4.z, p4.w};
                #pragma unroll
                for (int u = 0; u < 4; ++u)
                    #pragma unroll
                    for (int j = 0; j < 4; ++j)
                        o_acc[i][j] += pp[u] * vv[u][j];
            }
        }
    }

    #pragma unroll
    for (int i = 0; i < 4; ++i) {
        const float inv = 1.0f / l_run[i];
        float4 o = make_float4(o_acc[i][0] * inv, o_acc[i][1] * inv,
                               o_acc[i][2] * inv, o_acc[i][3] * inv);
        *((float4*)(R + ((size_t)b * NTOK + n0 + ty * 4 + i) * HCH + tx * 4)) = o;
    }
}

// ---------------------------------------------------------------------------
// Kernel 3: output projection with the torch-faithful layout reinterpretation.
// Since 64 | 1600:  out[b][c][h*25+t] = sum_j res[b][t*64+j][h] * wo[j][c]
// One block per (b, h); res column h staged in LDS; 512 c across 2 iterations.
// ---------------------------------------------------------------------------
extern "C" __global__ void __launch_bounds__(256) outproj_kernel(
    const float* __restrict__ Rm, const float* __restrict__ wo,
    float* __restrict__ out)
{
    const int b   = blockIdx.x >> 6;
    const int h   = blockIdx.x & 63;
    const int tid = threadIdx.x;

    __shared__ __align__(16) float resL[NTOK];
    for (int n = tid; n < NTOK; n += 256)
        resL[n] = Rm[((size_t)b * NTOK + n) * HCH + h];
    __syncthreads();

    #pragma unroll
    for (int it = 0; it < 2; ++it) {
        const int c = it * 256 + tid;
        float acc[25];
        #pragma unroll
        for (int t = 0; t < 25; ++t) acc[t] = 0.f;

        for (int j4 = 0; j4 < 16; ++j4) {
            const float w0 = wo[(size_t)(j4 * 4 + 0) * CIN + c];
            const float w1 = wo[(size_t)(j4 * 4 + 1) * CIN + c];
            const float w2 = wo[(size_t)(j4 * 4 + 2) * CIN + c];
            const float w3 = wo[(size_t)(j4 * 4 + 3) * CIN + c];
            #pragma unroll
            for (int t = 0; t < 25; ++t) {
                const float4 r4 = ((const float4*)resL)[t * 16 + j4];  // broadcast
                acc[t] += r4.x * w0 + r4.y * w1 + r4.z * w2 + r4.w * w3;
            }
        }
        float* op = out + ((size_t)b * CIN + c) * NTOK + h * 25;
        #pragma unroll
        for (int t = 0; t < 25; ++t) op[t] = acc[t];
    }
}

// ---------------------------------------------------------------------------
extern "C" void kernel_launch(void* const* d_in, const int* in_sizes, int n_in,
                              void* d_out, int out_size, void* d_ws, size_t ws_size,
                              hipStream_t stream)
{
    const float* rgb = (const float*)d_in[0];
    const float* hsi = (const float*)d_in[1];
    const float* wq  = (const float*)d_in[2];
    const float* wk  = (const float*)d_in[3];
    const float* wv  = (const float*)d_in[4];
    const float* wo  = (const float*)d_in[5];
    float* out = (float*)d_out;

    // scratch: Q, K, V, R  each [B][N][HC] f32 = 6.55 MB -> 26.2 MB total
    float* Qb = (float*)d_ws;
    float* Kb = Qb + (size_t)NB * NTOK * HCH;
    float* Vb = Kb + (size_t)NB * NTOK * HCH;
    float* Rb = Vb + (size_t)NB * NTOK * HCH;

    proj_kernel<<<dim3(NB * 25, 3), 256, 0, stream>>>(rgb, hsi, wq, wk, wv, Qb, Kb, Vb);
    attn_kernel<<<dim3(NB * 25), 256, 0, stream>>>(Qb, Kb, Vb, Rb);
    outproj_kernel<<<dim3(NB * 64), 256, 0, stream>>>(Rb, wo, out);
}

// Round 2
// 298.488 us; speedup vs baseline: 1.7209x; 1.7209x over previous
//
#include <hip/hip_runtime.h>
#include <cstddef>

#define NB   16
#define CIN  512
#define NTOK 1600   // 40*40
#define HCH  64
#define LDA  72     // padded LDS row stride (elements) for 64-wide k tiles

typedef __attribute__((ext_vector_type(8))) short bf16x8;
typedef __attribute__((ext_vector_type(4))) float f32x4;

__device__ __forceinline__ unsigned short f2bf(float x) {
    union { float f; unsigned u; } v; v.f = x;
    unsigned r = v.u + 0x7FFFu + ((v.u >> 16) & 1u);   // round-nearest-even
    return (unsigned short)(r >> 16);
}

// ---------------------------------------------------------------------------
// Prep: weights -> bf16, transposed to k(=c or j)-minor layouts.
// Wt[3][64h][512c] = {wq,wk,wv}^T ; WoT[512c][64j] = wo^T
// ---------------------------------------------------------------------------
__global__ void __launch_bounds__(256) wprep_kernel(
    const float* __restrict__ wq, const float* __restrict__ wk,
    const float* __restrict__ wv, const float* __restrict__ wo,
    unsigned short* __restrict__ Wt, unsigned short* __restrict__ WoT)
{
    const int blk = blockIdx.x, tid = threadIdx.x;
    if (blk < 3) {
        const float* w = (blk == 0) ? wq : (blk == 1) ? wk : wv;
        for (int idx = tid; idx < CIN * HCH; idx += 256) {
            int c = idx >> 6, h = idx & 63;                 // w[c][h], coalesced read
            Wt[(size_t)blk * HCH * CIN + (size_t)h * CIN + c] = f2bf(w[idx]);
        }
    } else {
        for (int idx = tid; idx < HCH * CIN; idx += 256) {
            int j = idx >> 9, c = idx & 511;                // wo[j][c], coalesced read
            WoT[(size_t)c * HCH + j] = f2bf(wo[idx]);
        }
    }
}

// ---------------------------------------------------------------------------
// Projections (MFMA): per block (b, 64-row n-tile), computes Q,K (from rgb)
// and V (from hsi), K-loop over c in chunks of 64 with in-LDS f32->bf16
// transpose of the token tiles.
//   Q,K stored [b][n][h] bf16 ; V stored transposed Vt[b][h][n] bf16
// ---------------------------------------------------------------------------
__global__ void __launch_bounds__(256) proj_kernel(
    const float* __restrict__ rgb, const float* __restrict__ hsi,
    const unsigned short* __restrict__ Wt,
    unsigned short* __restrict__ Q, unsigned short* __restrict__ K,
    unsigned short* __restrict__ Vt)
{
    __shared__ unsigned short As0[64 * LDA];       // rgb tokens  [n][c] c-minor
    __shared__ unsigned short As1[64 * LDA];       // hsi tokens  [n][c]
    __shared__ unsigned short Ws[3 * 64 * LDA];    // weights     [t][h][c]

    const int b    = blockIdx.x / 25;
    const int n0   = (blockIdx.x % 25) * 64;
    const int tid  = threadIdx.x;
    const int wv_  = tid >> 6;
    const int lane = tid & 63;
    const int l16  = lane & 15, quad = lane >> 4;

    f32x4 acc[3][4];
    #pragma unroll
    for (int t = 0; t < 3; ++t)
        #pragma unroll
        for (int nt = 0; nt < 4; ++nt)
            #pragma unroll
            for (int r = 0; r < 4; ++r) acc[t][nt][r] = 0.f;

    const int cc  = tid >> 2;          // 0..63 channel within chunk (staging)
    const int nq  = tid & 3;

    for (int c0 = 0; c0 < CIN; c0 += 64) {
        __syncthreads();
        // --- stage token tiles with transpose (f32 -> bf16) ---
        {
            const float* gr = rgb + ((size_t)b * CIN + c0 + cc) * NTOK + n0;
            const float* gh = hsi + ((size_t)b * CIN + c0 + cc) * NTOK + n0;
            #pragma unroll
            for (int rep = 0; rep < 4; ++rep) {
                const int nn4 = rep * 4 + nq;              // float4 index in row
                const float4 a = ((const float4*)gr)[nn4];
                const float4 h = ((const float4*)gh)[nn4];
                const int n = nn4 * 4;
                As0[(n + 0) * LDA + cc] = f2bf(a.x);
                As0[(n + 1) * LDA + cc] = f2bf(a.y);
                As0[(n + 2) * LDA + cc] = f2bf(a.z);
                As0[(n + 3) * LDA + cc] = f2bf(a.w);
                As1[(n + 0) * LDA + cc] = f2bf(h.x);
                As1[(n + 1) * LDA + cc] = f2bf(h.y);
                As1[(n + 2) * LDA + cc] = f2bf(h.z);
                As1[(n + 3) * LDA + cc] = f2bf(h.w);
            }
        }
        // --- stage weight tiles (already bf16, k-minor) ---
        #pragma unroll
        for (int r = 0; r < 6; ++r) {
            const int task = tid + r * 256;        // 0..1535
            const int row  = task >> 3;            // 0..191 = t*64 + h
            const int ch   = task & 7;
            *((int4*)(Ws + row * LDA + ch * 8)) =
                *((const int4*)(Wt + (size_t)row * CIN + c0 + ch * 8));
        }
        __syncthreads();

        // --- MFMA ---
        #pragma unroll
        for (int k0 = 0; k0 < 2; ++k0) {
            const bf16x8 a0 = *((const bf16x8*)(As0 + (wv_ * 16 + l16) * LDA + k0 * 32 + quad * 8));
            const bf16x8 a1 = *((const bf16x8*)(As1 + (wv_ * 16 + l16) * LDA + k0 * 32 + quad * 8));
            #pragma unroll
            for (int t = 0; t < 3; ++t) {
                const bf16x8 av = (t == 2) ? a1 : a0;
                #pragma unroll
                for (int nt = 0; nt < 4; ++nt) {
                    const bf16x8 bv = *((const bf16x8*)(Ws + (t * 64 + nt * 16 + l16) * LDA + k0 * 32 + quad * 8));
                    acc[t][nt] = __builtin_amdgcn_mfma_f32_16x16x32_bf16(av, bv, acc[t][nt], 0, 0, 0);
                }
            }
        }
    }

    // --- stores ---
    #pragma unroll
    for (int nt = 0; nt < 4; ++nt) {
        const int h = nt * 16 + l16;
        #pragma unroll
        for (int r = 0; r < 4; ++r) {
            const int n = n0 + wv_ * 16 + quad * 4 + r;
            Q[((size_t)b * NTOK + n) * HCH + h] = f2bf(acc[0][nt][r]);
            K[((size_t)b * NTOK + n) * HCH + h] = f2bf(acc[1][nt][r]);
        }
        ushort4 pv;
        pv.x = f2bf(acc[2][nt][0]); pv.y = f2bf(acc[2][nt][1]);
        pv.z = f2bf(acc[2][nt][2]); pv.w = f2bf(acc[2][nt][3]);
        *((ushort4*)(Vt + ((size_t)b * HCH + h) * NTOK + n0 + wv_ * 16 + quad * 4)) = pv;
    }
}

// ---------------------------------------------------------------------------
// Flash attention (MFMA). Block = (b, 64-query tile t). Output written as
// Rt2[b][t][h][j] bf16 (j = query within tile), j-minor for the out-proj GEMM.
// ---------------------------------------------------------------------------
__global__ void __launch_bounds__(256) attn_kernel(
    const unsigned short* __restrict__ Q, const unsigned short* __restrict__ K,
    const unsigned short* __restrict__ Vt, unsigned short* __restrict__ Rt2)
{
    __shared__ unsigned short Qs[64 * LDA];
    __shared__ unsigned short Ks[64 * LDA];   // [key][h]
    __shared__ unsigned short Vs[64 * LDA];   // [h][key]
    __shared__ unsigned short Ps[64 * LDA];   // per-wave strips [q_local][key]

    const int b    = blockIdx.x / 25;
    const int tq   = blockIdx.x % 25;
    const int n0   = tq * 64;
    const int tid  = threadIdx.x;
    const int wv_  = tid >> 6;
    const int lane = tid & 63;
    const int l16  = lane & 15, quad = lane >> 4;

    const unsigned short* Qg  = Q  + (size_t)b * NTOK * HCH;
    const unsigned short* Kg  = K  + (size_t)b * NTOK * HCH;
    const unsigned short* Vg  = Vt + (size_t)b * HCH * NTOK;

    // stage Q tile once
    #pragma unroll
    for (int r = 0; r < 2; ++r) {
        const int task = tid + r * 256;
        const int row = task >> 3, ch = task & 7;
        *((int4*)(Qs + row * LDA + ch * 8)) =
            *((const int4*)(Qg + ((size_t)(n0 + row)) * HCH + ch * 8));
    }

    float m_run[4], l_run[4];
    f32x4 o[4];
    #pragma unroll
    for (int r = 0; r < 4; ++r) { m_run[r] = -1e30f; l_run[r] = 0.f; }
    #pragma unroll
    for (int nt = 0; nt < 4; ++nt)
        #pragma unroll
        for (int r = 0; r < 4; ++r) o[nt][r] = 0.f;

    for (int kt = 0; kt < 25; ++kt) {
        __syncthreads();
        #pragma unroll
        for (int r = 0; r < 2; ++r) {
            const int task = tid + r * 256;
            const int row = task >> 3, ch = task & 7;
            *((int4*)(Ks + row * LDA + ch * 8)) =
                *((const int4*)(Kg + ((size_t)(kt * 64 + row)) * HCH + ch * 8));
            *((int4*)(Vs + row * LDA + ch * 8)) =
                *((const int4*)(Vg + (size_t)row * NTOK + kt * 64 + ch * 8));
        }
        __syncthreads();

        // S = Q K^T  (per wave: 16 q-rows x 64 keys)
        f32x4 s[4];
        #pragma unroll
        for (int nt = 0; nt < 4; ++nt)
            #pragma unroll
            for (int r = 0; r < 4; ++r) s[nt][r] = 0.f;
        #pragma unroll
        for (int k0 = 0; k0 < 2; ++k0) {
            const bf16x8 a = *((const bf16x8*)(Qs + (wv_ * 16 + l16) * LDA + k0 * 32 + quad * 8));
            #pragma unroll
            for (int nt = 0; nt < 4; ++nt) {
                const bf16x8 bv = *((const bf16x8*)(Ks + (nt * 16 + l16) * LDA + k0 * 32 + quad * 8));
                s[nt] = __builtin_amdgcn_mfma_f32_16x16x32_bf16(a, bv, s[nt], 0, 0, 0);
            }
        }

        // online softmax (rows = quad*4 + r, cols across nt & 16 lanes of quad)
        #pragma unroll
        for (int r = 0; r < 4; ++r) {
            float mx = -1e30f;
            #pragma unroll
            for (int nt = 0; nt < 4; ++nt) {
                s[nt][r] *= 0.125f;
                mx = fmaxf(mx, s[nt][r]);
            }
            #pragma unroll
            for (int msk = 1; msk < 16; msk <<= 1)
                mx = fmaxf(mx, __shfl_xor(mx, msk, 16));
            const float mn = fmaxf(m_run[r], mx);
            const float al = __expf(m_run[r] - mn);
            float rs = 0.f;
            #pragma unroll
            for (int nt = 0; nt < 4; ++nt) {
                const float e = __expf(s[nt][r] - mn);
                s[nt][r] = e; rs += e;
            }
            #pragma unroll
            for (int msk = 1; msk < 16; msk <<= 1)
                rs += __shfl_xor(rs, msk, 16);
            l_run[r] = l_run[r] * al + rs;
            m_run[r] = mn;
            #pragma unroll
            for (int nt = 0; nt < 4; ++nt) {
                o[nt][r] *= al;
                // P: C-layout -> A-layout via per-wave-private LDS strip
                Ps[(wv_ * 16 + quad * 4 + r) * LDA + nt * 16 + l16] = f2bf(s[nt][r]);
            }
        }

        // O += P V   (A from Ps, B from Vs) — same-wave LDS, no barrier needed
        #pragma unroll
        for (int k0 = 0; k0 < 2; ++k0) {
            const bf16x8 a = *((const bf16x8*)(Ps + (wv_ * 16 + l16) * LDA + k0 * 32 + quad * 8));
            #pragma unroll
            for (int nt = 0; nt < 4; ++nt) {
                const bf16x8 bv = *((const bf16x8*)(Vs + (nt * 16 + l16) * LDA + k0 * 32 + quad * 8));
                o[nt] = __builtin_amdgcn_mfma_f32_16x16x32_bf16(a, bv, o[nt], 0, 0, 0);
            }
        }
    }

    // epilogue: normalize, store Rt2[b][t][h][j]  (j = wv_*16 + quad*4 + r)
    unsigned short* Rg = Rt2 + ((size_t)(b * 25 + tq) * HCH) * HCH;
    #pragma unroll
    for (int nt = 0; nt < 4; ++nt) {
        const int h = nt * 16 + l16;
        ushort4 pk;
        pk.x = f2bf(o[nt][0] / l_run[0]);
        pk.y = f2bf(o[nt][1] / l_run[1]);
        pk.z = f2bf(o[nt][2] / l_run[2]);
        pk.w = f2bf(o[nt][3] / l_run[3]);
        *((ushort4*)(Rg + (size_t)h * HCH + wv_ * 16 + quad * 4)) = pk;
    }
}

// ---------------------------------------------------------------------------
// Output projection (MFMA): out[b][c][h*25+t] = sum_j wo[j][c] * Rt2[b][t][h][j]
// Per-b GEMM: M=512 (c), N=1600 (n = h*25+t), K=64 (j).
// Grid (16 b, 8 c-tiles, 5 n-chunks of 5x64).
// ---------------------------------------------------------------------------
__global__ void __launch_bounds__(256) outproj_kernel(
    const unsigned short* __restrict__ Rt2, const unsigned short* __restrict__ WoT,
    float* __restrict__ out)
{
    __shared__ unsigned short Aw[64 * LDA];   // [c_local][j]

    const int b  = blockIdx.x;
    const int ct = blockIdx.y;
    const int zz = blockIdx.z;
    const int tid  = threadIdx.x;
    const int wv_  = tid >> 6;
    const int lane = tid & 63;
    const int l16  = lane & 15, quad = lane >> 4;

    #pragma unroll
    for (int r = 0; r < 2; ++r) {
        const int task = tid + r * 256;
        const int row = task >> 3, ch = task & 7;
        *((int4*)(Aw + row * LDA + ch * 8)) =
            *((const int4*)(WoT + ((size_t)(ct * 64 + row)) * HCH + ch * 8));
    }
    __syncthreads();

    for (int nt64 = zz * 5; nt64 < zz * 5 + 5; ++nt64) {
        const int n = nt64 * 64 + wv_ * 16 + l16;
        const int h = n / 25, t = n % 25;
        const unsigned short* bsrc = Rt2 + ((size_t)(b * 25 + t) * HCH + h) * HCH;

        f32x4 acc[4];
        #pragma unroll
        for (int mt = 0; mt < 4; ++mt)
            #pragma unroll
            for (int r = 0; r < 4; ++r) acc[mt][r] = 0.f;

        #pragma unroll
        for (int k0 = 0; k0 < 2; ++k0) {
            const bf16x8 bv = *((const bf16x8*)(bsrc + k0 * 32 + quad * 8));
            #pragma unroll
            for (int mt = 0; mt < 4; ++mt) {
                const bf16x8 av = *((const bf16x8*)(Aw + (mt * 16 + l16) * LDA + k0 * 32 + quad * 8));
                acc[mt] = __builtin_amdgcn_mfma_f32_16x16x32_bf16(av, bv, acc[mt], 0, 0, 0);
            }
        }
        #pragma unroll
        for (int mt = 0; mt < 4; ++mt)
            #pragma unroll
            for (int r = 0; r < 4; ++r)
                out[((size_t)b * CIN + ct * 64 + mt * 16 + quad * 4 + r) * NTOK + n] = acc[mt][r];
    }
}

// ---------------------------------------------------------------------------
extern "C" void kernel_launch(void* const* d_in, const int* in_sizes, int n_in,
                              void* d_out, int out_size, void* d_ws, size_t ws_size,
                              hipStream_t stream)
{
    const float* rgb = (const float*)d_in[0];
    const float* hsi = (const float*)d_in[1];
    const float* wq  = (const float*)d_in[2];
    const float* wk  = (const float*)d_in[3];
    const float* wv  = (const float*)d_in[4];
    const float* wo  = (const float*)d_in[5];
    float* out = (float*)d_out;

    // ws layout (bf16 elements): Wt[3*64*512] WoT[512*64] Q K Vt Rt2 — 13.4 MB
    unsigned short* Wt  = (unsigned short*)d_ws;
    unsigned short* WoT = Wt  + (size_t)3 * HCH * CIN;
    unsigned short* Qb  = WoT + (size_t)CIN * HCH;
    unsigned short* Kb  = Qb  + (size_t)NB * NTOK * HCH;
    unsigned short* Vtb = Kb  + (size_t)NB * NTOK * HCH;
    unsigned short* Rt2 = Vtb + (size_t)NB * NTOK * HCH;

    wprep_kernel<<<dim3(4), 256, 0, stream>>>(wq, wk, wv, wo, Wt, WoT);
    proj_kernel<<<dim3(NB * 25), 256, 0, stream>>>(rgb, hsi, Wt, Qb, Kb, Vtb);
    attn_kernel<<<dim3(NB * 25), 256, 0, stream>>>(Qb, Kb, Vtb, Rt2);
    outproj_kernel<<<dim3(NB, 8, 5), 256, 0, stream>>>(Rt2, WoT, out);
}

// Round 3
// 246.026 us; speedup vs baseline: 2.0878x; 1.2132x over previous
//
#include <hip/hip_runtime.h>
#include <cstddef>

#define NB   16
#define CIN  512
#define NTOK 1600   // 40*40
#define HCH  64
#define LDA  72     // padded LDS row stride (bf16 elems), mult of 8 for 16B loads

typedef __attribute__((ext_vector_type(8))) short bf16x8;
typedef __attribute__((ext_vector_type(4))) float f32x4;

__device__ __forceinline__ unsigned short f2bf(float x) {
    union { float f; unsigned u; } v; v.f = x;
    unsigned r = v.u + 0x7FFFu + ((v.u >> 16) & 1u);   // round-nearest-even
    return (unsigned short)(r >> 16);
}

// ---------------------------------------------------------------------------
// Weight prep: Wt[3][64h][512c] = {wq,wk,wv}^T ; WoT[512c][64j] = wo^T
// 16384 threads, one int4 (8 bf16) output each; reads coalesced (lane->h / c).
// ---------------------------------------------------------------------------
__global__ void __launch_bounds__(256) wprep_kernel(
    const float* __restrict__ wq, const float* __restrict__ wk,
    const float* __restrict__ wv, const float* __restrict__ wo,
    unsigned short* __restrict__ Wt, unsigned short* __restrict__ WoT)
{
    const int gid = blockIdx.x * 256 + threadIdx.x;
    if (gid < 3 * HCH * (CIN / 8)) {               // 12288 Wt threads
        const int h  = gid & 63;
        const int c8 = (gid >> 6) & 63;
        const int t  = gid >> 12;
        const float* w = (t == 0) ? wq : (t == 1) ? wk : wv;
        ushort4 lo, hi;
        lo.x = f2bf(w[(size_t)(c8 * 8 + 0) * HCH + h]);
        lo.y = f2bf(w[(size_t)(c8 * 8 + 1) * HCH + h]);
        lo.z = f2bf(w[(size_t)(c8 * 8 + 2) * HCH + h]);
        lo.w = f2bf(w[(size_t)(c8 * 8 + 3) * HCH + h]);
        hi.x = f2bf(w[(size_t)(c8 * 8 + 4) * HCH + h]);
        hi.y = f2bf(w[(size_t)(c8 * 8 + 5) * HCH + h]);
        hi.z = f2bf(w[(size_t)(c8 * 8 + 6) * HCH + h]);
        hi.w = f2bf(w[(size_t)(c8 * 8 + 7) * HCH + h]);
        ushort4* dst = (ushort4*)(Wt + ((size_t)t * HCH + h) * CIN + c8 * 8);
        dst[0] = lo; dst[1] = hi;
    } else {                                        // 4096 WoT threads
        const int g  = gid - 3 * HCH * (CIN / 8);
        const int c  = g & 511;
        const int j8 = g >> 9;
        ushort4 lo, hi;
        lo.x = f2bf(wo[(size_t)(j8 * 8 + 0) * CIN + c]);
        lo.y = f2bf(wo[(size_t)(j8 * 8 + 1) * CIN + c]);
        lo.z = f2bf(wo[(size_t)(j8 * 8 + 2) * CIN + c]);
        lo.w = f2bf(wo[(size_t)(j8 * 8 + 3) * CIN + c]);
        hi.x = f2bf(wo[(size_t)(j8 * 8 + 4) * CIN + c]);
        hi.y = f2bf(wo[(size_t)(j8 * 8 + 5) * CIN + c]);
        hi.z = f2bf(wo[(size_t)(j8 * 8 + 6) * CIN + c]);
        hi.w = f2bf(wo[(size_t)(j8 * 8 + 7) * CIN + c]);
        ushort4* dst = (ushort4*)(WoT + (size_t)c * HCH + j8 * 8);
        dst[0] = lo; dst[1] = hi;
    }
}

// ---------------------------------------------------------------------------
// Projections (MFMA). blockIdx.y==0: Q,K from rgb; ==1: V from hsi.
// Per block: (b, 64-token tile). K-loop over c in 64-chunks with in-LDS
// f32->bf16 transpose. Q,K stored [b][n][h]; V stored Vt[b][h][n].
// ---------------------------------------------------------------------------
__global__ void __launch_bounds__(256) proj_kernel(
    const float* __restrict__ rgb, const float* __restrict__ hsi,
    const unsigned short* __restrict__ Wt,
    unsigned short* __restrict__ Q, unsigned short* __restrict__ K,
    unsigned short* __restrict__ Vt)
{
    __shared__ __align__(16) unsigned short As[64 * LDA];
    __shared__ __align__(16) unsigned short Ws[128 * LDA];

    const int which = blockIdx.y;                 // 0: QK, 1: V
    const int b    = blockIdx.x / 25;
    const int n0   = (blockIdx.x % 25) * 64;
    const int tid  = threadIdx.x;
    const int wv_  = tid >> 6;
    const int lane = tid & 63;
    const int l16  = lane & 15, quad = lane >> 4;

    const float* __restrict__ src = which ? hsi : rgb;
    const unsigned short* __restrict__ wbase = Wt + (which ? (size_t)2 * HCH * CIN : 0);
    const int nW = which ? 1 : 2;

    f32x4 acc[2][4];
    #pragma unroll
    for (int t = 0; t < 2; ++t)
        #pragma unroll
        for (int nt = 0; nt < 4; ++nt)
            #pragma unroll
            for (int r = 0; r < 4; ++r) acc[t][nt][r] = 0.f;

    const int cc = tid >> 2;           // 0..63 channel row (staging)
    const int nq = tid & 3;

    for (int c0 = 0; c0 < CIN; c0 += 64) {
        __syncthreads();
        {   // token tile transpose f32 -> bf16, [n][c] c-minor
            const float* gs = src + ((size_t)b * CIN + c0 + cc) * NTOK + n0;
            #pragma unroll
            for (int rep = 0; rep < 4; ++rep) {
                const int nn4 = rep * 4 + nq;
                const float4 a = ((const float4*)gs)[nn4];
                const int n = nn4 * 4;
                As[(n + 0) * LDA + cc] = f2bf(a.x);
                As[(n + 1) * LDA + cc] = f2bf(a.y);
                As[(n + 2) * LDA + cc] = f2bf(a.z);
                As[(n + 3) * LDA + cc] = f2bf(a.w);
            }
        }
        // weight tiles (bf16, c-minor): nW*64 rows x 64 c = nW*512 int4 tasks
        for (int task = tid; task < nW * 512; task += 256) {
            const int row = task >> 3, ch = task & 7;
            *((int4*)(Ws + row * LDA + ch * 8)) =
                *((const int4*)(wbase + (size_t)row * CIN + c0 + ch * 8));
        }
        __syncthreads();

        #pragma unroll
        for (int k0 = 0; k0 < 2; ++k0) {
            const bf16x8 av = *((const bf16x8*)(As + (wv_ * 16 + l16) * LDA + k0 * 32 + quad * 8));
            if (which == 0) {
                #pragma unroll
                for (int t = 0; t < 2; ++t)
                    #pragma unroll
                    for (int nt = 0; nt < 4; ++nt) {
                        const bf16x8 bv = *((const bf16x8*)(Ws + (t * 64 + nt * 16 + l16) * LDA + k0 * 32 + quad * 8));
                        acc[t][nt] = __builtin_amdgcn_mfma_f32_16x16x32_bf16(av, bv, acc[t][nt], 0, 0, 0);
                    }
            } else {
                #pragma unroll
                for (int nt = 0; nt < 4; ++nt) {
                    const bf16x8 bv = *((const bf16x8*)(Ws + (nt * 16 + l16) * LDA + k0 * 32 + quad * 8));
                    acc[0][nt] = __builtin_amdgcn_mfma_f32_16x16x32_bf16(av, bv, acc[0][nt], 0, 0, 0);
                }
            }
        }
    }

    if (which == 0) {
        #pragma unroll
        for (int nt = 0; nt < 4; ++nt) {
            const int h = nt * 16 + l16;
            #pragma unroll
            for (int r = 0; r < 4; ++r) {
                const int n = n0 + wv_ * 16 + quad * 4 + r;
                Q[((size_t)b * NTOK + n) * HCH + h] = f2bf(acc[0][nt][r]);
                K[((size_t)b * NTOK + n) * HCH + h] = f2bf(acc[1][nt][r]);
            }
        }
    } else {
        #pragma unroll
        for (int nt = 0; nt < 4; ++nt) {
            const int h = nt * 16 + l16;
            ushort4 pv;
            pv.x = f2bf(acc[0][nt][0]); pv.y = f2bf(acc[0][nt][1]);
            pv.z = f2bf(acc[0][nt][2]); pv.w = f2bf(acc[0][nt][3]);
            *((ushort4*)(Vt + ((size_t)b * HCH + h) * NTOK + n0 + wv_ * 16 + quad * 4)) = pv;
        }
    }
}

// ---------------------------------------------------------------------------
// Flash attention, split-K across waves, barrier-free K-loop.
// Block = (b, 16-query tile qt of 100); 4 waves each process key tiles
// kt = w, w+4, ... reading K/V fragments straight from global (L2-resident).
// One final barrier merges the 4 partial online-softmax states.
// blockIdx.x = qt*16 + b  -> XCD (x%8) == b%8: per-batch K/V stays L2-local.
// ---------------------------------------------------------------------------
__global__ void __launch_bounds__(256) attn_kernel(
    const unsigned short* __restrict__ Q, const unsigned short* __restrict__ K,
    const unsigned short* __restrict__ Vt, unsigned short* __restrict__ Rt2)
{
    __shared__ __align__(16) unsigned short Ps[4 * 16 * LDA];  // per-wave P strips
    __shared__ float Osh[4][16][68];
    __shared__ float msh[4][16], lsh[4][16];

    const int b    = blockIdx.x & 15;
    const int qt   = blockIdx.x >> 4;          // 0..99
    const int tid  = threadIdx.x;
    const int wv_  = tid >> 6;
    const int lane = tid & 63;
    const int l16  = lane & 15, quad = lane >> 4;

    const unsigned short* Qg = Q  + ((size_t)b * NTOK + qt * 16) * HCH;
    const unsigned short* Kg = K  + (size_t)b * NTOK * HCH;
    const unsigned short* Vg = Vt + (size_t)b * HCH * NTOK;

    // Q A-fragments, held in registers for the whole kernel
    bf16x8 qa[2];
    #pragma unroll
    for (int k0 = 0; k0 < 2; ++k0)
        qa[k0] = *((const bf16x8*)(Qg + (size_t)l16 * HCH + k0 * 32 + quad * 8));

    float m_run[4], l_run[4];
    f32x4 o[4];
    #pragma unroll
    for (int r = 0; r < 4; ++r) { m_run[r] = -1e30f; l_run[r] = 0.f; }
    #pragma unroll
    for (int nt = 0; nt < 4; ++nt)
        #pragma unroll
        for (int r = 0; r < 4; ++r) o[nt][r] = 0.f;

    unsigned short* PsW = Ps + wv_ * 16 * LDA;

    for (int kt = wv_; kt < 25; kt += 4) {
        // ---- S = Q K^T ----
        f32x4 s[4];
        #pragma unroll
        for (int nt = 0; nt < 4; ++nt)
            #pragma unroll
            for (int r = 0; r < 4; ++r) s[nt][r] = 0.f;

        bf16x8 kb[2][4];
        #pragma unroll
        for (int k0 = 0; k0 < 2; ++k0)
            #pragma unroll
            for (int nt = 0; nt < 4; ++nt)
                kb[k0][nt] = *((const bf16x8*)(Kg + ((size_t)(kt * 64 + nt * 16 + l16)) * HCH + k0 * 32 + quad * 8));
        #pragma unroll
        for (int k0 = 0; k0 < 2; ++k0)
            #pragma unroll
            for (int nt = 0; nt < 4; ++nt)
                s[nt] = __builtin_amdgcn_mfma_f32_16x16x32_bf16(qa[k0], kb[k0][nt], s[nt], 0, 0, 0);

        // ---- online softmax (rows q = quad*4+r, cols across nt,l16) ----
        #pragma unroll
        for (int r = 0; r < 4; ++r) {
            float mx = -1e30f;
            #pragma unroll
            for (int nt = 0; nt < 4; ++nt) {
                s[nt][r] *= 0.125f;
                mx = fmaxf(mx, s[nt][r]);
            }
            #pragma unroll
            for (int msk = 1; msk < 16; msk <<= 1)
                mx = fmaxf(mx, __shfl_xor(mx, msk, 16));
            const float mn = fmaxf(m_run[r], mx);
            const float al = __expf(m_run[r] - mn);
            float rs = 0.f;
            #pragma unroll
            for (int nt = 0; nt < 4; ++nt) {
                const float e = __expf(s[nt][r] - mn);
                s[nt][r] = e; rs += e;
            }
            #pragma unroll
            for (int msk = 1; msk < 16; msk <<= 1)
                rs += __shfl_xor(rs, msk, 16);
            l_run[r] = l_run[r] * al + rs;
            m_run[r] = mn;
            #pragma unroll
            for (int nt = 0; nt < 4; ++nt) {
                o[nt][r] *= al;
                PsW[(quad * 4 + r) * LDA + nt * 16 + l16] = f2bf(s[nt][r]);
            }
        }

        // ---- O += P V  (per-wave LDS strip, no barrier needed) ----
        bf16x8 vb[2][4];
        #pragma unroll
        for (int k0 = 0; k0 < 2; ++k0)
            #pragma unroll
            for (int nt = 0; nt < 4; ++nt)
                vb[k0][nt] = *((const bf16x8*)(Vg + ((size_t)(nt * 16 + l16)) * NTOK + kt * 64 + k0 * 32 + quad * 8));
        #pragma unroll
        for (int k0 = 0; k0 < 2; ++k0) {
            const bf16x8 pa = *((const bf16x8*)(PsW + l16 * LDA + k0 * 32 + quad * 8));
            #pragma unroll
            for (int nt = 0; nt < 4; ++nt)
                o[nt] = __builtin_amdgcn_mfma_f32_16x16x32_bf16(pa, vb[k0][nt], o[nt], 0, 0, 0);
        }
    }

    // ---- merge 4 partial states ----
    #pragma unroll
    for (int nt = 0; nt < 4; ++nt)
        #pragma unroll
        for (int r = 0; r < 4; ++r)
            Osh[wv_][quad * 4 + r][nt * 16 + l16] = o[nt][r];
    if (l16 == 0) {
        #pragma unroll
        for (int r = 0; r < 4; ++r) {
            msh[wv_][quad * 4 + r] = m_run[r];
            lsh[wv_][quad * 4 + r] = l_run[r];
        }
    }
    __syncthreads();

    // each wave recombines its h-strip: h = wv_*16 + l16, q = quad*4 + r
    const int t  = qt >> 2;
    const int j0 = (qt & 3) * 16;
    const int h  = wv_ * 16 + l16;
    ushort4 pk;
    unsigned short pkv[4];
    #pragma unroll
    for (int r = 0; r < 4; ++r) {
        const int q = quad * 4 + r;
        float mw[4], lw[4];
        float mstar = -1e30f;
        #pragma unroll
        for (int w = 0; w < 4; ++w) {
            mw[w] = msh[w][q]; lw[w] = lsh[w][q];
            mstar = fmaxf(mstar, mw[w]);
        }
        float L = 0.f, val = 0.f;
        #pragma unroll
        for (int w = 0; w < 4; ++w) {
            const float sc = __expf(mw[w] - mstar);
            L   += sc * lw[w];
            val += sc * Osh[w][q][h];
        }
        pkv[r] = f2bf(val / L);
    }
    pk.x = pkv[0]; pk.y = pkv[1]; pk.z = pkv[2]; pk.w = pkv[3];
    *((ushort4*)(Rt2 + (((size_t)(b * 25 + t) * HCH + h) * HCH) + j0 + quad * 4)) = pk;
}

// ---------------------------------------------------------------------------
// Output projection: out[b][c][h*25+t] = sum_j wo[j][c] * Rt2[b][t][h][j]
// 1-D grid: x = rest*16 + b  (XCD-clusters batches for Rt2 L2 locality)
// ---------------------------------------------------------------------------
__global__ void __launch_bounds__(256) outproj_kernel(
    const unsigned short* __restrict__ Rt2, const unsigned short* __restrict__ WoT,
    float* __restrict__ out)
{
    __shared__ __align__(16) unsigned short Aw[64 * LDA];

    const int b    = blockIdx.x & 15;
    const int rest = blockIdx.x >> 4;        // 0..39
    const int ct   = rest / 5;               // 0..7 c-tile
    const int zz   = rest % 5;               // 0..4 n-chunk
    const int tid  = threadIdx.x;
    const int wv_  = tid >> 6;
    const int lane = tid & 63;
    const int l16  = lane & 15, quad = lane >> 4;

    #pragma unroll
    for (int r = 0; r < 2; ++r) {
        const int task = tid + r * 256;
        const int row = task >> 3, ch = task & 7;
        *((int4*)(Aw + row * LDA + ch * 8)) =
            *((const int4*)(WoT + ((size_t)(ct * 64 + row)) * HCH + ch * 8));
    }
    __syncthreads();

    for (int nt64 = zz * 5; nt64 < zz * 5 + 5; ++nt64) {
        const int n = nt64 * 64 + wv_ * 16 + l16;
        const int h = n / 25, t = n % 25;
        const unsigned short* bsrc = Rt2 + ((size_t)(b * 25 + t) * HCH + h) * HCH;

        f32x4 acc[4];
        #pragma unroll
        for (int mt = 0; mt < 4; ++mt)
            #pragma unroll
            for (int r = 0; r < 4; ++r) acc[mt][r] = 0.f;

        #pragma unroll
        for (int k0 = 0; k0 < 2; ++k0) {
            const bf16x8 bv = *((const bf16x8*)(bsrc + k0 * 32 + quad * 8));
            #pragma unroll
            for (int mt = 0; mt < 4; ++mt) {
                const bf16x8 av = *((const bf16x8*)(Aw + (mt * 16 + l16) * LDA + k0 * 32 + quad * 8));
                acc[mt] = __builtin_amdgcn_mfma_f32_16x16x32_bf16(av, bv, acc[mt], 0, 0, 0);
            }
        }
        #pragma unroll
        for (int mt = 0; mt < 4; ++mt)
            #pragma unroll
            for (int r = 0; r < 4; ++r)
                out[((size_t)b * CIN + ct * 64 + mt * 16 + quad * 4 + r) * NTOK + n] = acc[mt][r];
    }
}

// ---------------------------------------------------------------------------
extern "C" void kernel_launch(void* const* d_in, const int* in_sizes, int n_in,
                              void* d_out, int out_size, void* d_ws, size_t ws_size,
                              hipStream_t stream)
{
    const float* rgb = (const float*)d_in[0];
    const float* hsi = (const float*)d_in[1];
    const float* wq  = (const float*)d_in[2];
    const float* wk  = (const float*)d_in[3];
    const float* wv  = (const float*)d_in[4];
    const float* wo  = (const float*)d_in[5];
    float* out = (float*)d_out;

    unsigned short* Wt  = (unsigned short*)d_ws;
    unsigned short* WoT = Wt  + (size_t)3 * HCH * CIN;
    unsigned short* Qb  = WoT + (size_t)CIN * HCH;
    unsigned short* Kb  = Qb  + (size_t)NB * NTOK * HCH;
    unsigned short* Vtb = Kb  + (size_t)NB * NTOK * HCH;
    unsigned short* Rt2 = Vtb + (size_t)NB * NTOK * HCH;

    wprep_kernel<<<dim3(64), 256, 0, stream>>>(wq, wk, wv, wo, Wt, WoT);
    proj_kernel<<<dim3(NB * 25, 2), 256, 0, stream>>>(rgb, hsi, Wt, Qb, Kb, Vtb);
    attn_kernel<<<dim3(NB * 100), 256, 0, stream>>>(Qb, Kb, Vtb, Rt2);
    outproj_kernel<<<dim3(NB * 40), 256, 0, stream>>>(Rt2, WoT, out);
}

// Round 4
// 213.588 us; speedup vs baseline: 2.4049x; 1.1519x over previous
//
#include <hip/hip_runtime.h>
#include <cstddef>

#define NB   16
#define CIN  512
#define NTOK 1600   // 40*40
#define HCH  64
#define LDA  72     // padded LDS row stride (bf16 elems), mult of 8 for 16B loads

typedef __attribute__((ext_vector_type(8))) short bf16x8;
typedef __attribute__((ext_vector_type(4))) float f32x4;

__device__ __forceinline__ unsigned short f2bf(float x) {
    union { float f; unsigned u; } v; v.f = x;
    unsigned r = v.u + 0x7FFFu + ((v.u >> 16) & 1u);   // round-nearest-even
    return (unsigned short)(r >> 16);
}

// ---------------------------------------------------------------------------
// Weight prep: Wt[3][64h][512c] = {wq,wk,wv}^T ; WoT[512c][64j] = wo^T
// ---------------------------------------------------------------------------
__global__ void __launch_bounds__(256) wprep_kernel(
    const float* __restrict__ wq, const float* __restrict__ wk,
    const float* __restrict__ wv, const float* __restrict__ wo,
    unsigned short* __restrict__ Wt, unsigned short* __restrict__ WoT)
{
    const int gid = blockIdx.x * 256 + threadIdx.x;
    if (gid < 3 * HCH * (CIN / 8)) {               // 12288 Wt threads
        const int h  = gid & 63;
        const int c8 = (gid >> 6) & 63;
        const int t  = gid >> 12;
        const float* w = (t == 0) ? wq : (t == 1) ? wk : wv;
        ushort4 lo, hi;
        lo.x = f2bf(w[(size_t)(c8 * 8 + 0) * HCH + h]);
        lo.y = f2bf(w[(size_t)(c8 * 8 + 1) * HCH + h]);
        lo.z = f2bf(w[(size_t)(c8 * 8 + 2) * HCH + h]);
        lo.w = f2bf(w[(size_t)(c8 * 8 + 3) * HCH + h]);
        hi.x = f2bf(w[(size_t)(c8 * 8 + 4) * HCH + h]);
        hi.y = f2bf(w[(size_t)(c8 * 8 + 5) * HCH + h]);
        hi.z = f2bf(w[(size_t)(c8 * 8 + 6) * HCH + h]);
        hi.w = f2bf(w[(size_t)(c8 * 8 + 7) * HCH + h]);
        ushort4* dst = (ushort4*)(Wt + ((size_t)t * HCH + h) * CIN + c8 * 8);
        dst[0] = lo; dst[1] = hi;
    } else {                                        // 4096 WoT threads
        const int g  = gid - 3 * HCH * (CIN / 8);
        const int c  = g & 511;
        const int j8 = g >> 9;
        ushort4 lo, hi;
        lo.x = f2bf(wo[(size_t)(j8 * 8 + 0) * CIN + c]);
        lo.y = f2bf(wo[(size_t)(j8 * 8 + 1) * CIN + c]);
        lo.z = f2bf(wo[(size_t)(j8 * 8 + 2) * CIN + c]);
        lo.w = f2bf(wo[(size_t)(j8 * 8 + 3) * CIN + c]);
        hi.x = f2bf(wo[(size_t)(j8 * 8 + 4) * CIN + c]);
        hi.y = f2bf(wo[(size_t)(j8 * 8 + 5) * CIN + c]);
        hi.z = f2bf(wo[(size_t)(j8 * 8 + 6) * CIN + c]);
        hi.w = f2bf(wo[(size_t)(j8 * 8 + 7) * CIN + c]);
        ushort4* dst = (ushort4*)(WoT + (size_t)c * HCH + j8 * 8);
        dst[0] = lo; dst[1] = hi;
    }
}

// ---------------------------------------------------------------------------
// Projections (MFMA). blockIdx.y==0: Q,K from rgb; ==1: V from hsi.
// Q is pre-scaled by 0.125/ln(2) so attention can use raw exp2.
// Q,K stored [b][n][h]; V stored Vt[b][h][n].
// ---------------------------------------------------------------------------
__global__ void __launch_bounds__(256) proj_kernel(
    const float* __restrict__ rgb, const float* __restrict__ hsi,
    const unsigned short* __restrict__ Wt,
    unsigned short* __restrict__ Q, unsigned short* __restrict__ K,
    unsigned short* __restrict__ Vt)
{
    __shared__ __align__(16) unsigned short As[64 * LDA];
    __shared__ __align__(16) unsigned short Ws[128 * LDA];

    const int which = blockIdx.y;                 // 0: QK, 1: V
    const int b    = blockIdx.x / 25;
    const int n0   = (blockIdx.x % 25) * 64;
    const int tid  = threadIdx.x;
    const int wv_  = tid >> 6;
    const int lane = tid & 63;
    const int l16  = lane & 15, quad = lane >> 4;

    const float* __restrict__ src = which ? hsi : rgb;
    const unsigned short* __restrict__ wbase = Wt + (which ? (size_t)2 * HCH * CIN : 0);
    const int nW = which ? 1 : 2;

    f32x4 acc[2][4];
    #pragma unroll
    for (int t = 0; t < 2; ++t)
        #pragma unroll
        for (int nt = 0; nt < 4; ++nt)
            #pragma unroll
            for (int r = 0; r < 4; ++r) acc[t][nt][r] = 0.f;

    const int cc = tid >> 2;           // 0..63 channel row (staging)
    const int nq = tid & 3;

    for (int c0 = 0; c0 < CIN; c0 += 64) {
        __syncthreads();
        {   // token tile transpose f32 -> bf16, [n][c] c-minor
            const float* gs = src + ((size_t)b * CIN + c0 + cc) * NTOK + n0;
            #pragma unroll
            for (int rep = 0; rep < 4; ++rep) {
                const int nn4 = rep * 4 + nq;
                const float4 a = ((const float4*)gs)[nn4];
                const int n = nn4 * 4;
                As[(n + 0) * LDA + cc] = f2bf(a.x);
                As[(n + 1) * LDA + cc] = f2bf(a.y);
                As[(n + 2) * LDA + cc] = f2bf(a.z);
                As[(n + 3) * LDA + cc] = f2bf(a.w);
            }
        }
        for (int task = tid; task < nW * 512; task += 256) {
            const int row = task >> 3, ch = task & 7;
            *((int4*)(Ws + row * LDA + ch * 8)) =
                *((const int4*)(wbase + (size_t)row * CIN + c0 + ch * 8));
        }
        __syncthreads();

        #pragma unroll
        for (int k0 = 0; k0 < 2; ++k0) {
            const bf16x8 av = *((const bf16x8*)(As + (wv_ * 16 + l16) * LDA + k0 * 32 + quad * 8));
            if (which == 0) {
                #pragma unroll
                for (int t = 0; t < 2; ++t)
                    #pragma unroll
                    for (int nt = 0; nt < 4; ++nt) {
                        const bf16x8 bv = *((const bf16x8*)(Ws + (t * 64 + nt * 16 + l16) * LDA + k0 * 32 + quad * 8));
                        acc[t][nt] = __builtin_amdgcn_mfma_f32_16x16x32_bf16(av, bv, acc[t][nt], 0, 0, 0);
                    }
            } else {
                #pragma unroll
                for (int nt = 0; nt < 4; ++nt) {
                    const bf16x8 bv = *((const bf16x8*)(Ws + (nt * 16 + l16) * LDA + k0 * 32 + quad * 8));
                    acc[0][nt] = __builtin_amdgcn_mfma_f32_16x16x32_bf16(av, bv, acc[0][nt], 0, 0, 0);
                }
            }
        }
    }

    if (which == 0) {
        const float qscale = 0.18033688f;          // 0.125 / ln(2)
        #pragma unroll
        for (int nt = 0; nt < 4; ++nt) {
            const int h = nt * 16 + l16;
            #pragma unroll
            for (int r = 0; r < 4; ++r) {
                const int n = n0 + wv_ * 16 + quad * 4 + r;
                Q[((size_t)b * NTOK + n) * HCH + h] = f2bf(acc[0][nt][r] * qscale);
                K[((size_t)b * NTOK + n) * HCH + h] = f2bf(acc[1][nt][r]);
            }
        }
    } else {
        #pragma unroll
        for (int nt = 0; nt < 4; ++nt) {
            const int h = nt * 16 + l16;
            ushort4 pv;
            pv.x = f2bf(acc[0][nt][0]); pv.y = f2bf(acc[0][nt][1]);
            pv.z = f2bf(acc[0][nt][2]); pv.w = f2bf(acc[0][nt][3]);
            *((ushort4*)(Vt + ((size_t)b * HCH + h) * NTOK + n0 + wv_ * 16 + quad * 4)) = pv;
        }
    }
}

// ---------------------------------------------------------------------------
// Attention, no-max softmax (exp2, scale pre-folded into Q), split-K.
// Block = (b, 32-query tile), 4 waves each process kt = w, w+4, ... with a
// barrier-free K-loop (double-buffered per-wave P strips). Final 2-barrier
// merge sums partial O and l across waves (no rescaling needed).
// ---------------------------------------------------------------------------
__global__ void __launch_bounds__(256) attn_kernel(
    const unsigned short* __restrict__ Q, const unsigned short* __restrict__ K,
    const unsigned short* __restrict__ Vt, unsigned short* __restrict__ Rt2)
{
    // Ps: 4 waves x 2 buffers x 32 rows x LDA  (36864 B), aliased with the
    // merge buffers Osh[4][32][68] f32 (34816 B) + lsh[4][32] (512 B).
    __shared__ __align__(16) unsigned char smem[4 * 2 * 32 * LDA * 2];

    const int b    = blockIdx.x & 15;
    const int qt   = blockIdx.x >> 4;          // 0..49 (32-query tiles)
    const int q0   = qt * 32;
    const int tid  = threadIdx.x;
    const int wv_  = tid >> 6;
    const int lane = tid & 63;
    const int l16  = lane & 15, quad = lane >> 4;

    const unsigned short* Qg = Q  + ((size_t)b * NTOK + q0) * HCH;
    const unsigned short* Kg = K  + (size_t)b * NTOK * HCH;
    const unsigned short* Vg = Vt + (size_t)b * HCH * NTOK;

    unsigned short* PsW = (unsigned short*)smem + wv_ * (2 * 32 * LDA);

    // Q A-fragments for both 16-row halves, in registers for the whole kernel
    bf16x8 qa[2][2];
    #pragma unroll
    for (int qh = 0; qh < 2; ++qh)
        #pragma unroll
        for (int k0 = 0; k0 < 2; ++k0)
            qa[qh][k0] = *((const bf16x8*)(Qg + (size_t)(qh * 16 + l16) * HCH + k0 * 32 + quad * 8));

    f32x4 o[2][4];
    float rs[2][4];
    #pragma unroll
    for (int qh = 0; qh < 2; ++qh) {
        #pragma unroll
        for (int r = 0; r < 4; ++r) rs[qh][r] = 0.f;
        #pragma unroll
        for (int nt = 0; nt < 4; ++nt)
            #pragma unroll
            for (int r = 0; r < 4; ++r) o[qh][nt][r] = 0.f;
    }

    int buf = 0;
    for (int kt = wv_; kt < 25; kt += 4, buf ^= 1) {
        unsigned short* Pb = PsW + buf * (32 * LDA);

        // ---- K and V fragments from global (L2-resident) ----
        bf16x8 kb[2][4], vb[2][4];
        #pragma unroll
        for (int k0 = 0; k0 < 2; ++k0)
            #pragma unroll
            for (int nt = 0; nt < 4; ++nt) {
                kb[k0][nt] = *((const bf16x8*)(Kg + ((size_t)(kt * 64 + nt * 16 + l16)) * HCH + k0 * 32 + quad * 8));
                vb[k0][nt] = *((const bf16x8*)(Vg + ((size_t)(nt * 16 + l16)) * NTOK + kt * 64 + k0 * 32 + quad * 8));
            }

        // ---- S = Q K^T ----
        f32x4 s[2][4];
        #pragma unroll
        for (int qh = 0; qh < 2; ++qh)
            #pragma unroll
            for (int nt = 0; nt < 4; ++nt)
                #pragma unroll
                for (int r = 0; r < 4; ++r) s[qh][nt][r] = 0.f;
        #pragma unroll
        for (int k0 = 0; k0 < 2; ++k0)
            #pragma unroll
            for (int qh = 0; qh < 2; ++qh)
                #pragma unroll
                for (int nt = 0; nt < 4; ++nt)
                    s[qh][nt] = __builtin_amdgcn_mfma_f32_16x16x32_bf16(qa[qh][k0], kb[k0][nt], s[qh][nt], 0, 0, 0);

        // ---- P = exp2(S), accumulate row sums, pack to LDS strip ----
        #pragma unroll
        for (int qh = 0; qh < 2; ++qh)
            #pragma unroll
            for (int r = 0; r < 4; ++r) {
                #pragma unroll
                for (int nt = 0; nt < 4; ++nt) {
                    const float e = exp2f(s[qh][nt][r]);
                    rs[qh][r] += e;
                    Pb[(qh * 16 + quad * 4 + r) * LDA + nt * 16 + l16] = f2bf(e);
                }
            }

        // ---- O += P V  (same-wave LDS, no barrier) ----
        #pragma unroll
        for (int k0 = 0; k0 < 2; ++k0)
            #pragma unroll
            for (int qh = 0; qh < 2; ++qh) {
                const bf16x8 pa = *((const bf16x8*)(Pb + (qh * 16 + l16) * LDA + k0 * 32 + quad * 8));
                #pragma unroll
                for (int nt = 0; nt < 4; ++nt)
                    o[qh][nt] = __builtin_amdgcn_mfma_f32_16x16x32_bf16(pa, vb[k0][nt], o[qh][nt], 0, 0, 0);
            }
    }

    // ---- reduce row sums across the 16 lanes of each row ----
    #pragma unroll
    for (int qh = 0; qh < 2; ++qh)
        #pragma unroll
        for (int r = 0; r < 4; ++r)
            #pragma unroll
            for (int msk = 1; msk < 16; msk <<= 1)
                rs[qh][r] += __shfl_xor(rs[qh][r], msk, 16);

    // ---- merge partial O / l across the 4 waves (aliased LDS) ----
    __syncthreads();                       // all waves done with Ps strips
    float* Osh = (float*)smem;             // [w*32+q][68]
    float* lsh = (float*)(smem + 4 * 32 * 68 * 4);
    #pragma unroll
    for (int qh = 0; qh < 2; ++qh) {
        #pragma unroll
        for (int nt = 0; nt < 4; ++nt)
            #pragma unroll
            for (int r = 0; r < 4; ++r)
                Osh[(size_t)(wv_ * 32 + qh * 16 + quad * 4 + r) * 68 + nt * 16 + l16] = o[qh][nt][r];
        if (l16 == 0)
            #pragma unroll
            for (int r = 0; r < 4; ++r)
                lsh[wv_ * 32 + qh * 16 + quad * 4 + r] = rs[qh][r];
    }
    __syncthreads();

    // each lane outputs h = wv_*16+l16 for 8 q rows; Rt2[b][t][h][j]
    const int t  = qt >> 1;
    const int jb = (qt & 1) * 32;
    const int h  = wv_ * 16 + l16;
    unsigned short* Rg = Rt2 + ((size_t)(b * 25 + t) * HCH + h) * HCH + jb;
    #pragma unroll
    for (int qh = 0; qh < 2; ++qh) {
        ushort4 pk;
        unsigned short pkv[4];
        #pragma unroll
        for (int r = 0; r < 4; ++r) {
            const int q = qh * 16 + quad * 4 + r;
            float val = 0.f, L = 0.f;
            #pragma unroll
            for (int w = 0; w < 4; ++w) {
                val += Osh[(size_t)(w * 32 + q) * 68 + h];
                L   += lsh[w * 32 + q];
            }
            pkv[r] = f2bf(val / L);
        }
        pk.x = pkv[0]; pk.y = pkv[1]; pk.z = pkv[2]; pk.w = pkv[3];
        *((ushort4*)(Rg + qh * 16 + quad * 4)) = pk;
    }
}

// ---------------------------------------------------------------------------
// Output projection: out[b][c][h*25+t] = sum_j wo[j][c] * Rt2[b][t][h][j]
// Grid (16 b, 8 c-tiles, 25 n-tiles): one 64x64 output tile per block.
// ---------------------------------------------------------------------------
__global__ void __launch_bounds__(256) outproj_kernel(
    const unsigned short* __restrict__ Rt2, const unsigned short* __restrict__ WoT,
    float* __restrict__ out)
{
    __shared__ __align__(16) unsigned short Aw[64 * LDA];

    const int b    = blockIdx.x;
    const int ct   = blockIdx.y;
    const int nt64 = blockIdx.z;
    const int tid  = threadIdx.x;
    const int wv_  = tid >> 6;
    const int lane = tid & 63;
    const int l16  = lane & 15, quad = lane >> 4;

    #pragma unroll
    for (int r = 0; r < 2; ++r) {
        const int task = tid + r * 256;
        const int row = task >> 3, ch = task & 7;
        *((int4*)(Aw + row * LDA + ch * 8)) =
            *((const int4*)(WoT + ((size_t)(ct * 64 + row)) * HCH + ch * 8));
    }
    __syncthreads();

    const int n = nt64 * 64 + wv_ * 16 + l16;
    const int h = n / 25, t = n % 25;
    const unsigned short* bsrc = Rt2 + ((size_t)(b * 25 + t) * HCH + h) * HCH;

    f32x4 acc[4];
    #pragma unroll
    for (int mt = 0; mt < 4; ++mt)
        #pragma unroll
        for (int r = 0; r < 4; ++r) acc[mt][r] = 0.f;

    #pragma unroll
    for (int k0 = 0; k0 < 2; ++k0) {
        const bf16x8 bv = *((const bf16x8*)(bsrc + k0 * 32 + quad * 8));
        #pragma unroll
        for (int mt = 0; mt < 4; ++mt) {
            const bf16x8 av = *((const bf16x8*)(Aw + (mt * 16 + l16) * LDA + k0 * 32 + quad * 8));
            acc[mt] = __builtin_amdgcn_mfma_f32_16x16x32_bf16(av, bv, acc[mt], 0, 0, 0);
        }
    }
    #pragma unroll
    for (int mt = 0; mt < 4; ++mt)
        #pragma unroll
        for (int r = 0; r < 4; ++r)
            out[((size_t)b * CIN + ct * 64 + mt * 16 + quad * 4 + r) * NTOK + n] = acc[mt][r];
}

// ---------------------------------------------------------------------------
extern "C" void kernel_launch(void* const* d_in, const int* in_sizes, int n_in,
                              void* d_out, int out_size, void* d_ws, size_t ws_size,
                              hipStream_t stream)
{
    const float* rgb = (const float*)d_in[0];
    const float* hsi = (const float*)d_in[1];
    const float* wq  = (const float*)d_in[2];
    const float* wk  = (const float*)d_in[3];
    const float* wv  = (const float*)d_in[4];
    const float* wo  = (const float*)d_in[5];
    float* out = (float*)d_out;

    unsigned short* Wt  = (unsigned short*)d_ws;
    unsigned short* WoT = Wt  + (size_t)3 * HCH * CIN;
    unsigned short* Qb  = WoT + (size_t)CIN * HCH;
    unsigned short* Kb  = Qb  + (size_t)NB * NTOK * HCH;
    unsigned short* Vtb = Kb  + (size_t)NB * NTOK * HCH;
    unsigned short* Rt2 = Vtb + (size_t)NB * NTOK * HCH;

    wprep_kernel<<<dim3(64), 256, 0, stream>>>(wq, wk, wv, wo, Wt, WoT);
    proj_kernel<<<dim3(NB * 25, 2), 256, 0, stream>>>(rgb, hsi, Wt, Qb, Kb, Vtb);
    attn_kernel<<<dim3(NB * 50), 256, 0, stream>>>(Qb, Kb, Vtb, Rt2);
    outproj_kernel<<<dim3(NB, 8, 25), 256, 0, stream>>>(Rt2, WoT, out);
}